// Round 1
// baseline (29.667 us; speedup 1.0000x reference)
//
#include <hip/hip_runtime.h>

// Reference reduces to: out[0] = mean(|pred - mask|) over 16*1024*1024 fp32
// elements. The Gaussian-conv loop in the reference is dead code (its result
// is never used by the returned loss). Pure memory-bound streaming reduction.

#define N_TOTAL (16u * 1024u * 1024u)   // 16,777,216 elements
#define NBLOCKS 2048
#define NTHREADS 256

__global__ __launch_bounds__(NTHREADS) void abs_diff_partial(
    const float4* __restrict__ pred,
    const float4* __restrict__ mask,
    float* __restrict__ partial) {
    const int n4 = (int)(N_TOTAL / 4);  // 4,194,304 float4
    float acc = 0.0f;
    for (int i = blockIdx.x * blockDim.x + threadIdx.x; i < n4;
         i += gridDim.x * blockDim.x) {
        float4 p = pred[i];
        float4 m = mask[i];
        acc += fabsf(p.x - m.x) + fabsf(p.y - m.y) +
               fabsf(p.z - m.z) + fabsf(p.w - m.w);
    }
    // wave-64 shuffle reduce
    #pragma unroll
    for (int off = 32; off > 0; off >>= 1)
        acc += __shfl_down(acc, off, 64);

    __shared__ float s[NTHREADS / 64];
    const int lane = threadIdx.x & 63;
    const int wid  = threadIdx.x >> 6;
    if (lane == 0) s[wid] = acc;
    __syncthreads();
    if (threadIdx.x == 0) {
        float b = 0.0f;
        #pragma unroll
        for (int w = 0; w < NTHREADS / 64; ++w) b += s[w];
        partial[blockIdx.x] = b;  // fixed order -> deterministic
    }
}

__global__ __launch_bounds__(NTHREADS) void final_reduce(
    const float* __restrict__ partial, float* __restrict__ out) {
    float acc = 0.0f;
    for (int i = threadIdx.x; i < NBLOCKS; i += NTHREADS)
        acc += partial[i];
    #pragma unroll
    for (int off = 32; off > 0; off >>= 1)
        acc += __shfl_down(acc, off, 64);

    __shared__ float s[NTHREADS / 64];
    const int lane = threadIdx.x & 63;
    const int wid  = threadIdx.x >> 6;
    if (lane == 0) s[wid] = acc;
    __syncthreads();
    if (threadIdx.x == 0) {
        float b = 0.0f;
        #pragma unroll
        for (int w = 0; w < NTHREADS / 64; ++w) b += s[w];
        out[0] = b / (float)N_TOTAL;
    }
}

extern "C" void kernel_launch(void* const* d_in, const int* in_sizes, int n_in,
                              void* d_out, int out_size, void* d_ws, size_t ws_size,
                              hipStream_t stream) {
    const float4* pred = (const float4*)d_in[0];
    const float4* mask = (const float4*)d_in[1];
    float* out = (float*)d_out;
    float* partial = (float*)d_ws;  // NBLOCKS floats = 8 KB scratch

    abs_diff_partial<<<NBLOCKS, NTHREADS, 0, stream>>>(pred, mask, partial);
    final_reduce<<<1, NTHREADS, 0, stream>>>(partial, out);
}